// Round 13
// baseline (236.789 us; speedup 1.0000x reference)
//
#include <hip/hip_runtime.h>

#define BATCH   131072
#define NHID    128
#define BM      32      // batch rows per tile
#define TPB     512     // 8 waves
#define NBLK    512     // 2 blocks/CU at <=128 unified regs
#define NTILE   (BATCH / BM)     // 4096
#define TPBLK   (NTILE / NBLK)   // 8 tiles per block

typedef __bf16 bf16_t;
typedef __bf16 bf16x8 __attribute__((ext_vector_type(8)));
typedef float  f32x4  __attribute__((ext_vector_type(4)));

__device__ __forceinline__ float fsigmoid(float v) {
    return __builtin_amdgcn_rcpf(1.0f + __builtin_amdgcn_exp2f(v * -1.44269504f));
}
__device__ __forceinline__ float ftanh(float v) {
    return __builtin_fmaf(-2.0f,
        __builtin_amdgcn_rcpf(1.0f + __builtin_amdgcn_exp2f(v * 2.88539008f)), 1.0f);
}
__device__ __forceinline__ f32x4 vsig(f32x4 v) {
    f32x4 r;
    #pragma unroll
    for (int i = 0; i < 4; ++i) r[i] = fsigmoid(v[i]);
    return r;
}
__device__ __forceinline__ f32x4 vtanh(f32x4 v) {
    f32x4 r;
    #pragma unroll
    for (int i = 0; i < 4; ++i) r[i] = ftanh(v[i]);
    return r;
}

// W4s: coalesced fragment-major pack of the 4 gate weights (bf16).
// o = (frag*64 + lane)*8 + e ; frag = (wv*8+ks)*4+pm ; lane = lq*16+l16
// maps to gate t=pm, out-col j=wv*16+l16, k=ks*32+lq*8+e.
// A wave's B-fragment load is then base + frag*512elems + lane*8elems -> 1KB
// fully coalesced per instruction.
__global__ void prep_kernel(const float* __restrict__ Wf, const float* __restrict__ Wi,
                            const float* __restrict__ Wc, const float* __restrict__ Wo,
                            const float* __restrict__ bfp, const float* __restrict__ bip,
                            const float* __restrict__ bcp, const float* __restrict__ bop,
                            const float* __restrict__ Wfc,
                            bf16_t* __restrict__ W4s, float* __restrict__ b4p,
                            bf16_t* __restrict__ Wfcb)
{
    int id = blockIdx.x * 256 + threadIdx.x;
    if (id < 512 * 256) {
        const int e    = id & 7;
        const int lane = (id >> 3) & 63;
        const int l16  = lane & 15;
        const int lq   = lane >> 4;
        const int frag = id >> 9;
        const int pm   = frag & 3;          // gate
        const int ks   = (frag >> 2) & 7;
        const int wv   = frag >> 5;
        const int j    = wv * 16 + l16;     // output column
        const int k    = ks * 32 + lq * 8 + e;
        const float* W = (pm == 0) ? Wf : (pm == 1) ? Wi : (pm == 2) ? Wc : Wo;
        W4s[id] = (bf16_t)W[j * 256 + k];
    } else if (id < 512 * 256 + 128 * 128) {
        int id2 = id - 512 * 256;
        Wfcb[id2] = (bf16_t)Wfc[id2];
    } else if (id < 512 * 256 + 128 * 128 + 512) {
        int p = id - 512 * 256 - 128 * 128;
        int t = (p >> 4) & 3, c = p & 15, w = p >> 6;
        int j = w * 16 + c;
        const float* bs = (t == 0) ? bfp : (t == 1) ? bip : (t == 2) ? bcp : bop;
        b4p[p] = bs[j];
    }
}

// K1: gates GEMM + LSTM elementwise. NO LDS, NO barriers, NO resident weight
// slab: B-fragments stream from L2 (coalesced W4s), A-fragments stream from
// global fp32 (8 waves/block share the tile -> L2-hit). Small per-wave state
// (<=128 unified regs) -> 16 waves/CU; TLP hides L2/HBM latency.
__global__ __launch_bounds__(TPB) void lstm_gates(
    const float* __restrict__ x, const float* __restrict__ hidden, const float* __restrict__ ctx,
    const bf16_t* __restrict__ W4s, const float* __restrict__ b4p,
    float* __restrict__ hid_out, float* __restrict__ ctx_out)
{
    const int tid  = threadIdx.x;
    const int lane = tid & 63;
    const int wv   = tid >> 6;     // 0..7
    const int l16  = lane & 15;
    const int lq   = lane >> 4;    // 0..3
    const int tile0 = blockIdx.x * TPBLK;
    const int colb  = wv * 16 + lq * 4;     // lane's 4 consecutive gate-cols

    // this wave's B slice: frags (wv*8+ks)*4+pm, per-lane 16B contiguous
    const bf16_t* Bw = W4s + ((size_t)(wv * 8) * 4) * 512 + (size_t)lane * 8;

    const f32x4 bf4 = *(const f32x4*)(b4p + wv * 64 +  0 + lq * 4);
    const f32x4 bi4 = *(const f32x4*)(b4p + wv * 64 + 16 + lq * 4);
    const f32x4 bc4 = *(const f32x4*)(b4p + wv * 64 + 32 + lq * 4);
    const f32x4 bo4 = *(const f32x4*)(b4p + wv * 64 + 48 + lq * 4);

    f32x4 ctxA[2], ctxB[2];
    {   // prologue: ctx for tile 0
        const float* cp = ctx + (size_t)(tile0 * BM) * NHID + colb;
        ctxA[0] = *(const f32x4*)(cp + (size_t)l16 * NHID);
        ctxA[1] = *(const f32x4*)(cp + (size_t)(16 + l16) * NHID);
    }

    for (int t = 0; t < TPBLK; ++t) {
        const int row0 = (tile0 + t) * BM;

        // prefetch next tile's ctx (retires during this tile's GEMM)
        {
            const int tn = (t + 1 < TPBLK) ? t + 1 : TPBLK - 1;
            const float* cp = ctx + (size_t)((tile0 + tn) * BM) * NHID + colb;
            ctxB[0] = *(const f32x4*)(cp + (size_t)l16 * NHID);
            ctxB[1] = *(const f32x4*)(cp + (size_t)(16 + l16) * NHID);
        }

        // GEMM1 (transposed): gates^T = W4 . cat^T ; acc[pm][bn]
        f32x4 acc[4][2];
        #pragma unroll
        for (int pm = 0; pm < 4; ++pm) {
            acc[pm][0] = f32x4{0.f, 0.f, 0.f, 0.f};
            acc[pm][1] = f32x4{0.f, 0.f, 0.f, 0.f};
        }
        #pragma unroll
        for (int ks = 0; ks < 8; ++ks) {
            // A-fragments: fp32 from global (L2-shared across the 8 waves)
            bf16x8 a[2];
            #pragma unroll
            for (int bn = 0; bn < 2; ++bn) {
                const size_t rr = (size_t)(row0 + bn * 16 + l16) * NHID;
                const float* s = (ks < 4)
                    ? (hidden + rr + ks * 32 + lq * 8)
                    : (x      + rr + (ks - 4) * 32 + lq * 8);
                f32x4 f0 = *(const f32x4*)(s);
                f32x4 f1 = *(const f32x4*)(s + 4);
                a[bn][0] = (bf16_t)f0.x; a[bn][1] = (bf16_t)f0.y;
                a[bn][2] = (bf16_t)f0.z; a[bn][3] = (bf16_t)f0.w;
                a[bn][4] = (bf16_t)f1.x; a[bn][5] = (bf16_t)f1.y;
                a[bn][6] = (bf16_t)f1.z; a[bn][7] = (bf16_t)f1.w;
            }
            // B-fragments: bf16 from L2, fully coalesced (1KB/instr)
            bf16x8 b[4];
            #pragma unroll
            for (int pm = 0; pm < 4; ++pm)
                b[pm] = *(const bf16x8*)(Bw + (size_t)(ks * 4 + pm) * 512);
            #pragma unroll
            for (int pm = 0; pm < 4; ++pm) {
                acc[pm][0] = __builtin_amdgcn_mfma_f32_16x16x32_bf16(b[pm], a[0], acc[pm][0], 0, 0, 0);
                acc[pm][1] = __builtin_amdgcn_mfma_f32_16x16x32_bf16(b[pm], a[1], acc[pm][1], 0, 0, 0);
            }
        }

        // fused LSTM elementwise; vectorized immediate stores
        #pragma unroll
        for (int bn = 0; bn < 2; ++bn) {
            const size_t grow = (size_t)(row0 + bn * 16 + l16) * NHID + colb;
            const f32x4 fv = vsig(acc[0][bn] + bf4);
            const f32x4 iv = vsig(acc[1][bn] + bi4);
            const f32x4 cv = vtanh(acc[2][bn] + bc4);
            const f32x4 ov = vsig(acc[3][bn] + bo4);
            const f32x4 cn = fv * ctxA[bn] + iv * cv;
            const f32x4 hn = ov * vtanh(cn);
            *(f32x4*)(ctx_out + grow) = cn;
            *(f32x4*)(hid_out + grow) = hn;
        }
        ctxA[0] = ctxB[0];
        ctxA[1] = ctxB[1];
    }
}

// K2: out = hidden_new @ Wfc^T + bfc. Streaming GEMM, high occupancy.
__global__ __launch_bounds__(256, 4) void fc_out(
    const float* __restrict__ hid, const bf16_t* __restrict__ Wfcb,
    const float* __restrict__ bfc, float* __restrict__ out)
{
    const int tid  = threadIdx.x;
    const int lane = tid & 63;
    const int wq   = tid >> 6;     // 0..3 -> 32-col group
    const int l16  = lane & 15;
    const int lq   = lane >> 4;    // 0..3
    const int row0 = blockIdx.x * 32;

    bf16x8 Wr[2][4];
    #pragma unroll
    for (int pm = 0; pm < 2; ++pm)
        #pragma unroll
        for (int ks = 0; ks < 4; ++ks)
            Wr[pm][ks] = *(const bf16x8*)(Wfcb + (wq * 32 + pm * 16 + l16) * 128 + ks * 32 + lq * 8);
    const f32x4 b0 = *(const f32x4*)(bfc + wq * 32 +  0 + lq * 4);
    const f32x4 b1 = *(const f32x4*)(bfc + wq * 32 + 16 + lq * 4);

    f32x4 acc[2][2];
    #pragma unroll
    for (int pm = 0; pm < 2; ++pm) {
        acc[pm][0] = f32x4{0.f, 0.f, 0.f, 0.f};
        acc[pm][1] = f32x4{0.f, 0.f, 0.f, 0.f};
    }
    #pragma unroll
    for (int bn = 0; bn < 2; ++bn) {
        const float* hr = hid + (size_t)(row0 + bn * 16 + l16) * NHID;
        #pragma unroll
        for (int ks = 0; ks < 4; ++ks) {
            f32x4 f0 = *(const f32x4*)(hr + ks * 32 + lq * 8);
            f32x4 f1 = *(const f32x4*)(hr + ks * 32 + lq * 8 + 4);
            bf16x8 h;
            h[0] = (bf16_t)f0.x; h[1] = (bf16_t)f0.y;
            h[2] = (bf16_t)f0.z; h[3] = (bf16_t)f0.w;
            h[4] = (bf16_t)f1.x; h[5] = (bf16_t)f1.y;
            h[6] = (bf16_t)f1.z; h[7] = (bf16_t)f1.w;
            acc[0][bn] = __builtin_amdgcn_mfma_f32_16x16x32_bf16(Wr[0][ks], h, acc[0][bn], 0, 0, 0);
            acc[1][bn] = __builtin_amdgcn_mfma_f32_16x16x32_bf16(Wr[1][ks], h, acc[1][bn], 0, 0, 0);
        }
    }
    #pragma unroll
    for (int bn = 0; bn < 2; ++bn) {
        const size_t grow = (size_t)(row0 + bn * 16 + l16) * NHID + wq * 32;
        *(f32x4*)(out + grow + lq * 4)      = acc[0][bn] + b0;
        *(f32x4*)(out + grow + 16 + lq * 4) = acc[1][bn] + b1;
    }
}

extern "C" void kernel_launch(void* const* d_in, const int* in_sizes, int n_in,
                              void* d_out, int out_size, void* d_ws, size_t ws_size,
                              hipStream_t stream) {
    const float* x      = (const float*)d_in[0];
    const float* hidden = (const float*)d_in[1];
    const float* ctx    = (const float*)d_in[2];
    const float* Wf     = (const float*)d_in[3];
    const float* bfp    = (const float*)d_in[4];
    const float* Wi     = (const float*)d_in[5];
    const float* bip    = (const float*)d_in[6];
    const float* Wc     = (const float*)d_in[7];
    const float* bcp    = (const float*)d_in[8];
    const float* Wo     = (const float*)d_in[9];
    const float* bop    = (const float*)d_in[10];
    const float* Wfc    = (const float*)d_in[11];
    const float* bfc    = (const float*)d_in[12];

    bf16_t* W4s  = (bf16_t*)d_ws;                                   // 262144 B
    bf16_t* Wfcb = (bf16_t*)((char*)d_ws + 512 * 256 * 2);          // 32768 B
    float*  b4p  = (float*)((char*)d_ws + 512 * 256 * 2 + 32768);   // 2048 B

    prep_kernel<<<578, 256, 0, stream>>>(Wf, Wi, Wc, Wo, bfp, bip, bcp, bop, Wfc,
                                         W4s, b4p, Wfcb);

    float* outp    = (float*)d_out;
    float* hid_out = outp + (size_t)BATCH * NHID;
    float* ctx_out = outp + 2 * (size_t)BATCH * NHID;

    lstm_gates<<<NBLK, TPB, 0, stream>>>(x, hidden, ctx, W4s, b4p, hid_out, ctx_out);
    fc_out<<<NTILE, 256, 0, stream>>>(hid_out, Wfcb, bfc, outp);
}

// Round 14
// 151.843 us; speedup vs baseline: 1.5594x; 1.5594x over previous
//
#include <hip/hip_runtime.h>

#define BATCH   131072
#define NHID    128
#define KDIM    256
#define BM      32      // batch rows per tile
#define TPB     512     // 8 waves
#define NBLK    512     // 2 blocks/CU if regs allow
#define NTILE   (BATCH / BM)     // 4096
#define TPBLK   (NTILE / NBLK)   // 8 tiles per block

typedef __bf16 bf16_t;
typedef __bf16 bf16x4 __attribute__((ext_vector_type(4)));
typedef __bf16 bf16x8 __attribute__((ext_vector_type(8)));
typedef float  f32x4  __attribute__((ext_vector_type(4)));

__device__ __forceinline__ float fsigmoid(float v) {
    return __builtin_amdgcn_rcpf(1.0f + __builtin_amdgcn_exp2f(v * -1.44269504f));
}
__device__ __forceinline__ float ftanh(float v) {
    return __builtin_fmaf(-2.0f,
        __builtin_amdgcn_rcpf(1.0f + __builtin_amdgcn_exp2f(v * 2.88539008f)), 1.0f);
}
__device__ __forceinline__ f32x4 vsig(f32x4 v) {
    f32x4 r;
    #pragma unroll
    for (int i = 0; i < 4; ++i) r[i] = fsigmoid(v[i]);
    return r;
}
__device__ __forceinline__ f32x4 vtanh(f32x4 v) {
    f32x4 r;
    #pragma unroll
    for (int i = 0; i < 4; ++i) r[i] = ftanh(v[i]);
    return r;
}

// W4s: coalesced fragment-major pack (bf16): o=(frag*64+lane)*8+e,
// frag=(wv*8+ks)*4+pm -> gate pm, out-col j=wv*16+l16, k=ks*32+lq*8+e.
__global__ void prep_kernel(const float* __restrict__ Wf, const float* __restrict__ Wi,
                            const float* __restrict__ Wc, const float* __restrict__ Wo,
                            const float* __restrict__ bfp, const float* __restrict__ bip,
                            const float* __restrict__ bcp, const float* __restrict__ bop,
                            const float* __restrict__ Wfc,
                            bf16_t* __restrict__ W4s, float* __restrict__ b4p,
                            bf16_t* __restrict__ Wfcb)
{
    int id = blockIdx.x * 256 + threadIdx.x;
    if (id < 512 * 256) {
        const int e    = id & 7;
        const int lane = (id >> 3) & 63;
        const int l16  = lane & 15;
        const int lq   = lane >> 4;
        const int frag = id >> 9;
        const int pm   = frag & 3;
        const int ks   = (frag >> 2) & 7;
        const int wv   = frag >> 5;
        const int j    = wv * 16 + l16;
        const int k    = ks * 32 + lq * 8 + e;
        const float* W = (pm == 0) ? Wf : (pm == 1) ? Wi : (pm == 2) ? Wc : Wo;
        W4s[id] = (bf16_t)W[j * 256 + k];
    } else if (id < 512 * 256 + 128 * 128) {
        int id2 = id - 512 * 256;
        Wfcb[id2] = (bf16_t)Wfc[id2];
    } else if (id < 512 * 256 + 128 * 128 + 512) {
        int p = id - 512 * 256 - 128 * 128;
        int t = (p >> 4) & 3, c = p & 15, w = p >> 6;
        int j = w * 16 + c;
        const float* bs = (t == 0) ? bfp : (t == 1) ? bip : (t == 2) ? bcp : bop;
        b4p[p] = bs[j];
    }
}

// K1: gates GEMM + LSTM. LDS-staged A (coalesced loads, proven r6), streamed
// coalesced B from L2 (proven r13) -- no resident weight slab, targeting
// <=128 unified regs so TWO 8-wave blocks co-reside per CU with independent
// barrier groups.
__global__ __launch_bounds__(TPB) void lstm_gates(
    const float* __restrict__ x, const float* __restrict__ hidden, const float* __restrict__ ctx,
    const bf16_t* __restrict__ W4s, const float* __restrict__ b4p,
    float* __restrict__ hid_out, float* __restrict__ ctx_out)
{
    // As[2]: bf16 [32][256] XOR-swizzled (2x16 KB) = 32 KB/block
    __shared__ __align__(16) char lds[2 * 16384];

    const int tid  = threadIdx.x;
    const int lane = tid & 63;
    const int wv   = tid >> 6;     // 0..7
    const int l16  = lane & 15;
    const int lq   = lane >> 4;    // 0..3
    const int tile0 = blockIdx.x * TPBLK;
    const int colb  = wv * 16 + lq * 4;
    const int swzA  = (l16 & 7) << 4;

    // stage mapping (r6 verbatim)
    const int r_s = tid >> 4;      // 0..31
    const int c_s = tid & 15;
    const int swzS = (r_s & 7) << 4;

    // wave's coalesced B slice base
    const bf16_t* Bw = W4s + (size_t)(wv * 32) * 512 + (size_t)lane * 8;

    const f32x4 bf4 = *(const f32x4*)(b4p + wv * 64 +  0 + lq * 4);
    const f32x4 bi4 = *(const f32x4*)(b4p + wv * 64 + 16 + lq * 4);
    const f32x4 bc4 = *(const f32x4*)(b4p + wv * 64 + 32 + lq * 4);
    const f32x4 bo4 = *(const f32x4*)(b4p + wv * 64 + 48 + lq * 4);

    f32x4 sv0, sv1, sv2, sv3;   // stage regs (tile t+1)
    f32x4 ctxA[2];              // ctx for tile t (loaded at tile top)

    // ---- prologue: stage tile0 -> As[0] ----
    {
        const int grow = tile0 * BM + r_s;
        const float* hrow = hidden + (size_t)grow * NHID + c_s * 4;
        const float* xrow = x      + (size_t)grow * NHID + c_s * 4;
        f32x4 t0 = *(const f32x4*)(hrow);
        f32x4 t1 = *(const f32x4*)(hrow + 64);
        f32x4 t2 = *(const f32x4*)(xrow);
        f32x4 t3 = *(const f32x4*)(xrow + 64);
        char* A0 = lds;
        bf16x4 p0, p1, p2, p3;
        p0[0]=(bf16_t)t0.x; p0[1]=(bf16_t)t0.y; p0[2]=(bf16_t)t0.z; p0[3]=(bf16_t)t0.w;
        p1[0]=(bf16_t)t1.x; p1[1]=(bf16_t)t1.y; p1[2]=(bf16_t)t1.z; p1[3]=(bf16_t)t1.w;
        p2[0]=(bf16_t)t2.x; p2[1]=(bf16_t)t2.y; p2[2]=(bf16_t)t2.z; p2[3]=(bf16_t)t2.w;
        p3[0]=(bf16_t)t3.x; p3[1]=(bf16_t)t3.y; p3[2]=(bf16_t)t3.z; p3[3]=(bf16_t)t3.w;
        *(bf16x4*)(A0 + r_s * 512 + ((c_s * 8 +   0) ^ swzS)) = p0;
        *(bf16x4*)(A0 + r_s * 512 + ((c_s * 8 + 128) ^ swzS)) = p1;
        *(bf16x4*)(A0 + r_s * 512 + ((c_s * 8 + 256) ^ swzS)) = p2;
        *(bf16x4*)(A0 + r_s * 512 + ((c_s * 8 + 384) ^ swzS)) = p3;
    }
    __syncthreads();

    for (int t = 0; t < TPBLK; ++t) {
        const int P = t & 1;
        const int row0 = (tile0 + t) * BM;
        char* Asb = lds + P * 16384;

        // ---- TOP: issue stage loads (t+1) + ctx loads (t) ----
        {
            const int tn = (t + 1 < TPBLK) ? t + 1 : TPBLK - 1;
            const int grow = (tile0 + tn) * BM + r_s;
            const float* hrow = hidden + (size_t)grow * NHID + c_s * 4;
            const float* xrow = x      + (size_t)grow * NHID + c_s * 4;
            sv0 = *(const f32x4*)(hrow);
            sv1 = *(const f32x4*)(hrow + 64);
            sv2 = *(const f32x4*)(xrow);
            sv3 = *(const f32x4*)(xrow + 64);
            const float* cp = ctx + (size_t)row0 * NHID + colb;
            ctxA[0] = *(const f32x4*)(cp + (size_t)l16 * NHID);
            ctxA[1] = *(const f32x4*)(cp + (size_t)(16 + l16) * NHID);
        }

        // ---- GEMM1 (transposed): gates^T = W4 . A^T ; B streamed from L2 ----
        f32x4 acc[4][2];
        #pragma unroll
        for (int pm = 0; pm < 4; ++pm) {
            acc[pm][0] = f32x4{0.f, 0.f, 0.f, 0.f};
            acc[pm][1] = f32x4{0.f, 0.f, 0.f, 0.f};
        }
        #pragma unroll
        for (int ks = 0; ks < 8; ++ks) {
            const int kb = ks * 64 + lq * 16;
            bf16x8 a0 = *(const bf16x8*)(Asb + l16 * 512        + (kb ^ swzA));
            bf16x8 a1 = *(const bf16x8*)(Asb + (16 + l16) * 512 + (kb ^ swzA));
            bf16x8 b[4];
            #pragma unroll
            for (int pm = 0; pm < 4; ++pm)
                b[pm] = *(const bf16x8*)(Bw + (size_t)(ks * 4 + pm) * 512);
            #pragma unroll
            for (int pm = 0; pm < 4; ++pm) {
                acc[pm][0] = __builtin_amdgcn_mfma_f32_16x16x32_bf16(b[pm], a0, acc[pm][0], 0, 0, 0);
                acc[pm][1] = __builtin_amdgcn_mfma_f32_16x16x32_bf16(b[pm], a1, acc[pm][1], 0, 0, 0);
            }
        }

        // ---- fused LSTM elementwise (4 gates in-lane), vectorized stores ----
        #pragma unroll
        for (int bn = 0; bn < 2; ++bn) {
            const size_t grow = (size_t)(row0 + bn * 16 + l16) * NHID + colb;
            const f32x4 fv = vsig(acc[0][bn] + bf4);
            const f32x4 iv = vsig(acc[1][bn] + bi4);
            const f32x4 cv = vtanh(acc[2][bn] + bc4);
            const f32x4 ov = vsig(acc[3][bn] + bo4);
            const f32x4 cn = fv * ctxA[bn] + iv * cv;
            const f32x4 hn = ov * vtanh(cn);
            *(f32x4*)(ctx_out + grow) = cn;
            *(f32x4*)(hid_out + grow) = hn;
        }

        // ---- stage write: tile t+1 -> As[P^1] ----
        {
            char* An = lds + (1 - P) * 16384;
            bf16x4 p0, p1, p2, p3;
            p0[0]=(bf16_t)sv0.x; p0[1]=(bf16_t)sv0.y; p0[2]=(bf16_t)sv0.z; p0[3]=(bf16_t)sv0.w;
            p1[0]=(bf16_t)sv1.x; p1[1]=(bf16_t)sv1.y; p1[2]=(bf16_t)sv1.z; p1[3]=(bf16_t)sv1.w;
            p2[0]=(bf16_t)sv2.x; p2[1]=(bf16_t)sv2.y; p2[2]=(bf16_t)sv2.z; p2[3]=(bf16_t)sv2.w;
            p3[0]=(bf16_t)sv3.x; p3[1]=(bf16_t)sv3.y; p3[2]=(bf16_t)sv3.z; p3[3]=(bf16_t)sv3.w;
            *(bf16x4*)(An + r_s * 512 + ((c_s * 8 +   0) ^ swzS)) = p0;
            *(bf16x4*)(An + r_s * 512 + ((c_s * 8 + 128) ^ swzS)) = p1;
            *(bf16x4*)(An + r_s * 512 + ((c_s * 8 + 256) ^ swzS)) = p2;
            *(bf16x4*)(An + r_s * 512 + ((c_s * 8 + 384) ^ swzS)) = p3;
        }

        __syncthreads();
    }
}

// K2: out = hidden_new @ Wfc^T + bfc. Streaming GEMM, high occupancy (proven).
__global__ __launch_bounds__(256, 4) void fc_out(
    const float* __restrict__ hid, const bf16_t* __restrict__ Wfcb,
    const float* __restrict__ bfc, float* __restrict__ out)
{
    const int tid  = threadIdx.x;
    const int lane = tid & 63;
    const int wq   = tid >> 6;
    const int l16  = lane & 15;
    const int lq   = lane >> 4;
    const int row0 = blockIdx.x * 32;

    bf16x8 Wr[2][4];
    #pragma unroll
    for (int pm = 0; pm < 2; ++pm)
        #pragma unroll
        for (int ks = 0; ks < 4; ++ks)
            Wr[pm][ks] = *(const bf16x8*)(Wfcb + (wq * 32 + pm * 16 + l16) * 128 + ks * 32 + lq * 8);
    const f32x4 b0 = *(const f32x4*)(bfc + wq * 32 +  0 + lq * 4);
    const f32x4 b1 = *(const f32x4*)(bfc + wq * 32 + 16 + lq * 4);

    f32x4 acc[2][2];
    #pragma unroll
    for (int pm = 0; pm < 2; ++pm) {
        acc[pm][0] = f32x4{0.f, 0.f, 0.f, 0.f};
        acc[pm][1] = f32x4{0.f, 0.f, 0.f, 0.f};
    }
    #pragma unroll
    for (int bn = 0; bn < 2; ++bn) {
        const float* hr = hid + (size_t)(row0 + bn * 16 + l16) * NHID;
        #pragma unroll
        for (int ks = 0; ks < 4; ++ks) {
            f32x4 f0 = *(const f32x4*)(hr + ks * 32 + lq * 8);
            f32x4 f1 = *(const f32x4*)(hr + ks * 32 + lq * 8 + 4);
            bf16x8 h;
            h[0] = (bf16_t)f0.x; h[1] = (bf16_t)f0.y;
            h[2] = (bf16_t)f0.z; h[3] = (bf16_t)f0.w;
            h[4] = (bf16_t)f1.x; h[5] = (bf16_t)f1.y;
            h[6] = (bf16_t)f1.z; h[7] = (bf16_t)f1.w;
            acc[0][bn] = __builtin_amdgcn_mfma_f32_16x16x32_bf16(Wr[0][ks], h, acc[0][bn], 0, 0, 0);
            acc[1][bn] = __builtin_amdgcn_mfma_f32_16x16x32_bf16(Wr[1][ks], h, acc[1][bn], 0, 0, 0);
        }
    }
    #pragma unroll
    for (int bn = 0; bn < 2; ++bn) {
        const size_t grow = (size_t)(row0 + bn * 16 + l16) * NHID + wq * 32;
        *(f32x4*)(out + grow + lq * 4)      = acc[0][bn] + b0;
        *(f32x4*)(out + grow + 16 + lq * 4) = acc[1][bn] + b1;
    }
}

extern "C" void kernel_launch(void* const* d_in, const int* in_sizes, int n_in,
                              void* d_out, int out_size, void* d_ws, size_t ws_size,
                              hipStream_t stream) {
    const float* x      = (const float*)d_in[0];
    const float* hidden = (const float*)d_in[1];
    const float* ctx    = (const float*)d_in[2];
    const float* Wf     = (const float*)d_in[3];
    const float* bfp    = (const float*)d_in[4];
    const float* Wi     = (const float*)d_in[5];
    const float* bip    = (const float*)d_in[6];
    const float* Wc     = (const float*)d_in[7];
    const float* bcp    = (const float*)d_in[8];
    const float* Wo     = (const float*)d_in[9];
    const float* bop    = (const float*)d_in[10];
    const float* Wfc    = (const float*)d_in[11];
    const float* bfc    = (const float*)d_in[12];

    bf16_t* W4s  = (bf16_t*)d_ws;                                   // 262144 B
    bf16_t* Wfcb = (bf16_t*)((char*)d_ws + 512 * 256 * 2);          // 32768 B
    float*  b4p  = (float*)((char*)d_ws + 512 * 256 * 2 + 32768);   // 2048 B

    prep_kernel<<<578, 256, 0, stream>>>(Wf, Wi, Wc, Wo, bfp, bip, bcp, bop, Wfc,
                                         W4s, b4p, Wfcb);

    float* outp    = (float*)d_out;
    float* hid_out = outp + (size_t)BATCH * NHID;
    float* ctx_out = outp + 2 * (size_t)BATCH * NHID;

    lstm_gates<<<NBLK, TPB, 0, stream>>>(x, hidden, ctx, W4s, b4p, hid_out, ctx_out);
    fc_out<<<NTILE, 256, 0, stream>>>(hid_out, Wfcb, bfc, outp);
}